// Round 1
// 503.861 us; speedup vs baseline: 1.0498x; 1.0498x over previous
//
#include <hip/hip_runtime.h>
#include <hip/hip_bf16.h>

// AngularBasis: real spherical harmonics l=0..7 for N points.
// OUTPUT IS FLOAT32 (harness compares after bf16-rounding both sides).
// Layout: 8 chunks [N, 2l+1] concatenated; chunk l starts at float N*l*l.
//
// v2: chunk-major LDS layout. Phase 1 writes each point's 64 values
// directly into the output-ordered position inside LDS:
//   lds[l*l*BLOCK + tid*(2l+1) + k]
// All chunk widths w = 2l+1 are ODD -> lane stride across LDS banks is odd
// -> coprime with 32 banks -> conflict-free (2 lanes/bank is free).
// Phase 2 is then a pure contiguous copy per chunk: ds_read_b128 +
// global_store_dwordx4 (16 B/lane), no div/mod, no remapping math.
// Roofline (our kernel): 512MB write + 16MB read @ ~6.3 TB/s ~= 84-90 us.

#define BLOCK 128

// (l+m)! / (l-m)! as double (max 14! = 8.7e10, exact in double)
static constexpr double kfac(int l, int m) {
    double f = 1.0;
    for (int k = l - m + 1; k <= l + m; ++k) f *= (double)k;
    return f;
}

__global__ __launch_bounds__(BLOCK) void sph_harm_f32(
    const float* __restrict__ ct, const float* __restrict__ ph,
    float* __restrict__ out, int N)
{
    __shared__ float lds[64 * BLOCK];  // 32768 B, output-ordered

    const int tid = threadIdx.x;
    const int bp0 = blockIdx.x * BLOCK;
    const int P_blk = min(BLOCK, N - bp0);  // N=2M, BLOCK=128 -> always 128

    // ---------------- Phase 1: per-point compute into LDS ----------------
    if (tid < P_blk) {
        const int n = bp0 + tid;
        const float x = ct[n];
        const float p = ph[n];
        float s2 = 1.0f - x * x;
        s2 = s2 < 0.0f ? 0.0f : s2;
        const float st = sqrtf(s2);  // sin(theta) >= 0

        float s1, c1;
        sincosf(p, &s1, &c1);
        float cm[8], sm[8];
        cm[0] = 1.0f; sm[0] = 0.0f;
#pragma unroll
        for (int m = 1; m <= 7; ++m) {
            cm[m] = cm[m - 1] * c1 - sm[m - 1] * s1;
            sm[m] = sm[m - 1] * c1 + cm[m - 1] * s1;
        }

        // Associated Legendre with Condon-Shortley phase (matches reference).
        float Pa[8][8];
        Pa[0][0] = 1.0f;
#pragma unroll
        for (int m = 1; m <= 7; ++m)
            Pa[m][m] = (float)(-(2 * m - 1)) * st * Pa[m - 1][m - 1];
#pragma unroll
        for (int m = 0; m <= 6; ++m)
            Pa[m + 1][m] = (float)(2 * m + 1) * x * Pa[m][m];
#pragma unroll
        for (int m = 0; m <= 7; ++m) {
#pragma unroll
            for (int l = m + 2; l <= 7; ++l) {
                Pa[l][m] = ((float)(2 * l - 1) * x * Pa[l - 1][m]
                            - (float)(l + m - 1) * Pa[l - 2][m])
                           / (float)(l - m);
            }
        }

        const double INV4PI = 0.07957747154594767;  // 1/(4*pi)
        const float SQRT2 = 1.4142135623730951f;
#pragma unroll
        for (int l = 0; l <= 7; ++l) {
            const int w = 2 * l + 1;
            // chunk-major, output-ordered slot for this point
            float* chunk = &lds[l * l * BLOCK + tid * w];
            const float K0 = sqrtf((float)((double)(2 * l + 1) * INV4PI));
            chunk[l] = K0 * Pa[l][0];  // m = 0 at column l
#pragma unroll
            for (int m = 1; m <= l; ++m) {
                const float Km = sqrtf(
                    (float)((double)(2 * l + 1) * INV4PI / kfac(l, m)));
                const float base = SQRT2 * Km * Pa[l][m];
                chunk[l - m] = base * sm[m];  // m<0 column (sin)
                chunk[l + m] = base * cm[m];  // m>0 column (cos)
            }
        }
    }
    __syncthreads();

    // ------------- Phase 2: contiguous float4 copy per chunk -------------
    // Chunk l block region: out[N*l*l + bp0*w ...), exactly P_blk*w floats,
    // and the LDS region lds[l*l*BLOCK ...) holds them in the same order.
    const size_t NN = (size_t)N;
    if (P_blk == BLOCK) {
        // bp0*w floats = 512*w bytes -> 16B aligned; lds chunk base l*l*128
        // floats -> 16B aligned. Pure vector copy.
#pragma unroll
        for (int l = 0; l <= 7; ++l) {
            const int w = 2 * l + 1;
            float4* __restrict__ cbase = reinterpret_cast<float4*>(
                out + NN * (size_t)(l * l) + (size_t)bp0 * (size_t)w);
            const float4* lsrc =
                reinterpret_cast<const float4*>(&lds[l * l * BLOCK]);
            const int cnt4 = (BLOCK / 4) * w;  // 32*w float4s
            for (int e = tid; e < cnt4; e += BLOCK)
                cbase[e] = lsrc[e];
        }
    } else {
        // Generic tail path (unused for N=2M): scalar contiguous copy.
#pragma unroll
        for (int l = 0; l <= 7; ++l) {
            const int w = 2 * l + 1;
            float* cbase = out + NN * (size_t)(l * l)
                           + (size_t)bp0 * (size_t)w;
            const float* lsrc = &lds[l * l * BLOCK];
            const int cnt = P_blk * w;
            for (int e = tid; e < cnt; e += BLOCK)
                cbase[e] = lsrc[e];
        }
    }
}

extern "C" void kernel_launch(void* const* d_in, const int* in_sizes, int n_in,
                              void* d_out, int out_size, void* d_ws, size_t ws_size,
                              hipStream_t stream) {
    const float* ct = (const float*)d_in[0];
    const float* ph = (const float*)d_in[1];
    // d_in[2] is l_max (==7), fixed at compile time.
    float* out = (float*)d_out;
    const int N = in_sizes[0];
    const int blocks = (N + BLOCK - 1) / BLOCK;
    hipLaunchKernelGGL(sph_harm_f32, dim3(blocks), dim3(BLOCK), 0, stream,
                       ct, ph, out, N);
}